// Round 2
// baseline (543.878 us; speedup 1.0000x reference)
//
#include <hip/hip_runtime.h>

// Problem dims
#define TOK   16384   // B*S
#define INFT  2048
#define HID   1024
#define CBD   32
#define NC    256
#define OUTF  2048

// ---------------------------------------------------------------------------
// ws layout (float offsets) — lifetime-sequenced aliasing
//  region A [0 .. 2,097,152):         up_wT (S1w, S2r)       [dead after S2]
//  region B [2,097,152 .. 3,145,728): part1 (S1w, S2r) -> T in first 524,288
//  WfT   [3,145,728 .. 3,211,264)   (S2w, mainr)
//  bf    [3,211,264 .. 3,211,296)   (S1w, mainr)
//  bpart [3,211,296 .. 3,227,680)   (S2w, tabler)   [8][2048]
//  part2 [3,311,648 .. 3,835,936)   (S2w, tabler)   [8][32][2048]
#define WS_UPWT   0
#define WS_PART1  2097152
#define WS_T      2097152
#define WS_WFT    3145728
#define WS_BF     3211264
#define WS_BPART  3211296
#define WS_PART2  3311648

// ---------------------------------------------------------------------------
// S1: blocks [0,2048) transpose up_w -> up_wT
//     blocks [2048,2176) WfT partials: part1[kc][c][2048] over h-chunks of 64
//     block  2176        bf[c] = pin_b[c] + pin_w @ down_b
__global__ __launch_bounds__(256) void k_stage1(
    const float* __restrict__ up_w, const float* __restrict__ pin_w,
    const float* __restrict__ pin_b, const float* __restrict__ down_w,
    const float* __restrict__ down_b, float* __restrict__ ws) {
    int bid = blockIdx.x, tid = threadIdx.x;
    if (bid < 2048) {
        __shared__ float tile[32][33];
        float* up_wT = ws + WS_UPWT;
        int h0 = (bid & 31) * 32;            // over HID
        int o0 = (bid >> 5) * 32;            // over OUTF
        int tx = tid & 31, ty = tid >> 5;    // 32x8
        #pragma unroll
        for (int j = 0; j < 32; j += 8)
            tile[ty + j][tx] = up_w[(o0 + ty + j) * HID + h0 + tx];
        __syncthreads();
        #pragma unroll
        for (int j = 0; j < 32; j += 8)
            up_wT[(h0 + ty + j) * OUTF + o0 + tx] = tile[tx][ty + j];
    } else if (bid < 2176) {
        float* part1 = ws + WS_PART1;
        int b  = bid - 2048;
        int i  = (b & 7) * 256 + tid;
        int k0 = (b >> 3) * 64;
        float acc[32];
        #pragma unroll
        for (int c = 0; c < 32; c++) acc[c] = 0.f;
        #pragma unroll 4
        for (int j = 0; j < 64; j++) {
            float xv = down_w[(k0 + j) * 2048 + i];
            #pragma unroll
            for (int c = 0; c < 32; c++)
                acc[c] = fmaf(pin_w[c * HID + k0 + j], xv, acc[c]);
        }
        #pragma unroll
        for (int c = 0; c < 32; c++)
            part1[((b >> 3) * 32 + c) * 2048 + i] = acc[c];
    } else {
        __shared__ float red[256];
        float* bf = ws + WS_BF;
        int c = tid >> 3, seg = tid & 7;
        float s = 0.f;
        #pragma unroll 8
        for (int k = seg * 128; k < seg * 128 + 128; k++)
            s = fmaf(pin_w[c * HID + k], down_b[k], s);
        red[tid] = s;
        __syncthreads();
        if (tid < 32) {
            float t = pin_b[tid];
            #pragma unroll
            for (int q = 0; q < 8; q++) t += red[tid * 8 + q];
            bf[tid] = t;
        }
    }
}

// ---------------------------------------------------------------------------
// S2: blocks [0,256)   WfT[i*32+c] = sum of 16 part1 partials
//     blocks [256,320) U2c partials part2[hc][c][2048] over h-chunks of 128,
//                      with bpart[hc][o] (bias2 partial) fused on the same xv
__global__ __launch_bounds__(256) void k_stage2(
    const float* __restrict__ pout_w, const float* __restrict__ pout_b,
    const float* __restrict__ up_b, float* __restrict__ ws) {
    int bid = blockIdx.x, tid = threadIdx.x;
    if (bid < 256) {
        const float* part1 = ws + WS_PART1;
        float* WfT = ws + WS_WFT;
        int f = bid * 256 + tid;             // 0..65535
        int i = f & 2047, c = f >> 11;
        float s = 0.f;
        #pragma unroll
        for (int b = 0; b < 16; b++) s += part1[b * 65536 + c * 2048 + i];
        WfT[i * 32 + c] = s;
    } else {
        const float* up_wT = ws + WS_UPWT;
        float* part2 = ws + WS_PART2;
        float* bpart = ws + WS_BPART;
        int b  = bid - 256;
        int i  = (b & 7) * 256 + tid;        // o
        int hc = b >> 3;                     // 0..7
        int k0 = hc * 128;
        float acc[32];
        #pragma unroll
        for (int c = 0; c < 32; c++) acc[c] = 0.f;
        float accb = 0.f;
        #pragma unroll 4
        for (int j = 0; j < 128; j++) {
            float xv = up_wT[(k0 + j) * 2048 + i];
            accb = fmaf(pout_b[k0 + j], xv, accb);   // bias2 fused: reuses xv
            #pragma unroll
            for (int c = 0; c < 32; c++)
                acc[c] = fmaf(pout_w[(k0 + j) * 32 + c], xv, acc[c]);
        }
        #pragma unroll
        for (int c = 0; c < 32; c++)
            part2[(hc * 32 + c) * 2048 + i] = acc[c];
        bpart[hc * 2048 + i] = accb + (hc == 0 ? up_b[i] : 0.f);
    }
}

// ---------------------------------------------------------------------------
// S3: table only (64 blocks): T[n][o] = sum_hc bpart + sum_c cb[n][c]*U2c[c][o]
//     (U2c reduced from part2 in-register; no U2c buffer)
__global__ __launch_bounds__(256) void k_table(
    const float* __restrict__ cb, float* __restrict__ ws) {
    const float* part2 = ws + WS_PART2;
    const float* bpart = ws + WS_BPART;
    float* T = ws + WS_T;
    int bid = blockIdx.x, tid = threadIdx.x;
    int o  = (bid & 7) * 256 + tid;
    int n0 = (bid >> 3) * 32;
    float u[32];
    #pragma unroll
    for (int c = 0; c < 32; c++) {
        float s = 0.f;
        #pragma unroll
        for (int kc = 0; kc < 8; kc++)
            s += part2[(kc * 32 + c) * 2048 + o];
        u[c] = s;
    }
    float bsum = 0.f;
    #pragma unroll
    for (int hc = 0; hc < 8; hc++) bsum += bpart[hc * 2048 + o];
    for (int n = n0; n < n0 + 32; n++) {
        float s = bsum;
        #pragma unroll
        for (int c = 0; c < 32; c++)
            s = fmaf(cb[n * 32 + c], u[c], s);       // cb wave-uniform -> s_load
        T[n * 2048 + o] = s;
    }
}

// ---------------------------------------------------------------------------
// S4 mega: full-k z GEMM (register double-buffered staging) + argmin + gather.
// 64 tokens/block, grid=256 (1 block/CU). Bit-identical z/idx/out vs the
// previous zpart->zred->gather path (same per-wave FMA order, same cross-wave
// reduce order per 512-k group, same (((bf+p0)+p1)+p2)+p3 accumulation).
__global__ __launch_bounds__(256) void k_main(
    const float* __restrict__ x, const float* __restrict__ cb,
    const float* __restrict__ ws, float* __restrict__ out,
    float* __restrict__ idx_f, float* __restrict__ loss) {
    // LDS pool with phase aliasing:
    //  z phase  : xs = float4[2113] @ 0        (33808 B)
    //  argmin   : cbs = float[256*36] @ 0      (36864 B, aliases xs)
    //  z_s   @ 36864 (9216 B)   cbn @ 46080 (1024 B)
    //  red_d @ 47104 (1024 B)   red_i @ 48128 (1024 B)   idx_s @ 49152 (256 B)
    __shared__ __align__(16) char pool[49408];
    float4* xs   = (float4*)pool;
    float*  cbs  = (float*)pool;
    float*  z_s  = (float*)(pool + 36864);
    float*  cbn  = (float*)(pool + 46080);
    float*  red_d = (float*)(pool + 47104);
    int*    red_i = (int*)(pool + 48128);
    int*    idx_s = (int*)(pool + 49152);

    const float* WfT = ws + WS_WFT;
    const float* bf  = ws + WS_BF;
    const float* T   = ws + WS_T;

    int tid  = threadIdx.x;
    int lane = tid & 63;
    int w    = __builtin_amdgcn_readfirstlane(tid >> 6);  // k-quarter 0..3
    int m0   = blockIdx.x * 64;
    const float* xb = x + (size_t)m0 * 2048;

    int tt = tid >> 2;            // token for reduce phase
    int cq = (tid & 3) * 8;       // c-octet for reduce phase

    // bias (read once; L2-resident)
    float bfv[8];
    {
        float4 b0 = *(const float4*)(bf + cq);
        float4 b1 = *(const float4*)(bf + cq + 4);
        bfv[0] = b0.x; bfv[1] = b0.y; bfv[2] = b0.z; bfv[3] = b0.w;
        bfv[4] = b1.x; bfv[5] = b1.y; bfv[6] = b1.z; bfv[7] = b1.w;
    }

    float acc[32];
    #pragma unroll
    for (int c = 0; c < 32; c++) acc[c] = 0.f;
    float stotal[8];

    // prologue: load chunk 0 (k = [0,128)) into registers
    float4 r[8];
    #pragma unroll
    for (int j = 0; j < 8; j++) {
        int f = j * 256 + tid;
        int t = f >> 5, q = f & 31;
        r[j] = *(const float4*)(xb + (size_t)t * 2048 + q * 4);
    }

    for (int kb = 0; kb < 4; kb++) {
        for (int sc = 0; sc < 4; sc++) {
            int ch = kb * 4 + sc;             // 0..15, k0 = ch*128
            __syncthreads();                  // xs free (prev reads done)
            // LDS-write current chunk (regs loaded during previous compute)
            #pragma unroll
            for (int j = 0; j < 8; j++) {
                int f = j * 256 + tid;
                int t = f >> 5, q = f & 31;
                xs[t * 33 + q] = r[j];
            }
            __syncthreads();                  // xs ready
            // issue next chunk's loads — HBM latency hides under compute
            if (ch < 15) {
                int k0n = (ch + 1) * 128;
                #pragma unroll
                for (int j = 0; j < 8; j++) {
                    int f = j * 256 + tid;
                    int t = f >> 5, q = f & 31;
                    r[j] = *(const float4*)(xb + (size_t)t * 2048 + k0n + q * 4);
                }
            }
            // compute: wave w owns k-subrange [w*32, w*32+32) of this chunk
            const float* wr = WfT + (size_t)(ch * 128 + w * 32) * 32;  // uniform
            #pragma unroll 2
            for (int j = 0; j < 8; j++) {
                float4 xv = xs[lane * 33 + w * 8 + j];
                #pragma unroll
                for (int c = 0; c < 32; c++) {
                    acc[c] = fmaf(wr[(j * 4 + 0) * 32 + c], xv.x, acc[c]);
                    acc[c] = fmaf(wr[(j * 4 + 1) * 32 + c], xv.y, acc[c]);
                    acc[c] = fmaf(wr[(j * 4 + 2) * 32 + c], xv.z, acc[c]);
                    acc[c] = fmaf(wr[(j * 4 + 3) * 32 + c], xv.w, acc[c]);
                }
            }
        }
        // cross-wave reduce for this 512-k group (exact old zpart order)
        __syncthreads();                      // all xs reads done -> rp writable
        float* rp = (float*)xs;
        #pragma unroll
        for (int c = 0; c < 32; c++)
            rp[(w * 64 + lane) * 33 + c] = acc[c];
        __syncthreads();
        #pragma unroll
        for (int j = 0; j < 8; j++) {
            float v = rp[(0 * 64 + tt) * 33 + cq + j];
            #pragma unroll
            for (int ww = 1; ww < 4; ww++) v += rp[(ww * 64 + tt) * 33 + cq + j];
            float base = (kb == 0) ? bfv[j] : stotal[j];
            stotal[j] = base + v;             // (((bf+p0)+p1)+p2)+p3
        }
        #pragma unroll
        for (int c = 0; c < 32; c++) acc[c] = 0.f;
    }

    // z -> LDS (z_s disjoint from xs region; no barrier needed before write)
    *(float4*)(z_s + tt * 36 + cq)     = make_float4(stotal[0], stotal[1], stotal[2], stotal[3]);
    *(float4*)(z_s + tt * 36 + cq + 4) = make_float4(stotal[4], stotal[5], stotal[6], stotal[7]);
    __syncthreads();                          // rp reads + z_s writes done

    // stage codebook (aliases xs — safe post-barrier), rows of 36
    #pragma unroll
    for (int j = 0; j < 8; j++) {
        int f = j * 256 + tid;                // float4 id, 2048 total
        int n = f >> 3, q = f & 7;
        float4 v = *(const float4*)(cb + n * 32 + q * 4);
        cbs[n * 36 + q * 4 + 0] = v.x;
        cbs[n * 36 + q * 4 + 1] = v.y;
        cbs[n * 36 + q * 4 + 2] = v.z;
        cbs[n * 36 + q * 4 + 3] = v.w;
    }
    __syncthreads();
    {   // cbn[n] = |cb_n|^2
        float s = 0.f;
        #pragma unroll
        for (int q = 0; q < 8; q++) {
            float4 v = *(const float4*)(&cbs[tid * 36 + q * 4]);
            s += v.x * v.x + v.y * v.y + v.z * v.z + v.w * v.w;
        }
        cbn[tid] = s;
    }
    __syncthreads();

    // token = lane, wave w scans codes [64w, 64w+64)
    float z[32];
    #pragma unroll
    for (int q = 0; q < 8; q++) {
        float4 v = *(const float4*)(&z_s[lane * 36 + q * 4]);
        z[q * 4 + 0] = v.x; z[q * 4 + 1] = v.y; z[q * 4 + 2] = v.z; z[q * 4 + 3] = v.w;
    }
    float bd = 3.4e38f; int bi = 0;
    for (int t = 0; t < 64; t++) {
        int n = w * 64 + t;                   // wave-uniform -> LDS broadcast
        float s = 0.f;
        #pragma unroll
        for (int q = 0; q < 8; q++) {
            float4 v = *(const float4*)(&cbs[n * 36 + q * 4]);
            s = fmaf(v.x, z[q * 4 + 0], s);
            s = fmaf(v.y, z[q * 4 + 1], s);
            s = fmaf(v.z, z[q * 4 + 2], s);
            s = fmaf(v.w, z[q * 4 + 3], s);
        }
        float d = fmaf(-2.f, s, cbn[n]);
        if (d < bd) { bd = d; bi = n; }       // strict < : first min wins
    }
    red_d[w * 64 + lane] = bd;
    red_i[w * 64 + lane] = bi;
    __syncthreads();
    if (tid < 64) {
        float d0 = red_d[tid]; int i0 = red_i[tid];
        #pragma unroll
        for (int ww = 1; ww < 4; ww++) {      // ascending wave = ascending code range
            float d1 = red_d[ww * 64 + tid];
            int   i1 = red_i[ww * 64 + tid];
            if (d1 < d0) { d0 = d1; i0 = i1; }
        }
        idx_s[tid] = i0;
        idx_f[m0 + tid] = (float)i0;
    }
    __syncthreads();

    // fused gather: write 64 rows of T (clipped); T is L2-resident (2 MB)
    const float4* T4 = (const float4*)T;
    float4* O4 = (float4*)(out + (size_t)m0 * 2048);
    #pragma unroll 2
    for (int rr = 0; rr < 64; rr++) {
        int n = idx_s[rr];
        const float4* Tr = T4 + (size_t)n * 512;
        float4 v0 = Tr[tid];
        float4 v1 = Tr[256 + tid];
        v0.x = fminf(fmaxf(v0.x, -1.f), 1.f);
        v0.y = fminf(fmaxf(v0.y, -1.f), 1.f);
        v0.z = fminf(fmaxf(v0.z, -1.f), 1.f);
        v0.w = fminf(fmaxf(v0.w, -1.f), 1.f);
        v1.x = fminf(fmaxf(v1.x, -1.f), 1.f);
        v1.y = fminf(fmaxf(v1.y, -1.f), 1.f);
        v1.z = fminf(fmaxf(v1.z, -1.f), 1.f);
        v1.w = fminf(fmaxf(v1.w, -1.f), 1.f);
        O4[(size_t)rr * 512 + tid]       = v0;
        O4[(size_t)rr * 512 + 256 + tid] = v1;
    }
    if (blockIdx.x == 0 && tid == 0) *loss = 0.f;
}

// ---------------------------------------------------------------------------
extern "C" void kernel_launch(void* const* d_in, const int* in_sizes, int n_in,
                              void* d_out, int out_size, void* d_ws, size_t ws_size,
                              hipStream_t stream) {
    const float* x      = (const float*)d_in[0];
    const float* down_w = (const float*)d_in[1];
    const float* down_b = (const float*)d_in[2];
    const float* pin_w  = (const float*)d_in[3];
    const float* pin_b  = (const float*)d_in[4];
    const float* cb     = (const float*)d_in[5];
    const float* pout_w = (const float*)d_in[6];
    const float* pout_b = (const float*)d_in[7];
    const float* up_w   = (const float*)d_in[8];
    const float* up_b   = (const float*)d_in[9];

    float* ws = (float*)d_ws;
    float* out_f  = (float*)d_out;                   // [16384][2048]
    float* idx_f  = out_f + (size_t)TOK * OUTF;      // [16384]
    float* loss_f = idx_f + TOK;                     // [1]

    k_stage1<<<2177, 256, 0, stream>>>(up_w, pin_w, pin_b, down_w, down_b, ws);
    k_stage2<<<320,  256, 0, stream>>>(pout_w, pout_b, up_b, ws);
    k_table<<<64,   256, 0, stream>>>(cb, ws);
    k_main<<<256,   256, 0, stream>>>(x, cb, ws, out_f, idx_f, loss_f);
}

// Round 3
// 451.202 us; speedup vs baseline: 1.2054x; 1.2054x over previous
//
#include <hip/hip_runtime.h>

// Problem dims
#define TOK   16384   // B*S
#define INFT  2048
#define HID   1024
#define CBD   32
#define NC    256
#define OUTF  2048
#define KB    4       // k-split chunks for z GEMM (512 k each)

// ---------------------------------------------------------------------------
// ws layout (float offsets) — lifetime-sequenced aliasing
//  region A [0 .. 2,097,152):         up_wT (S1w, S2r)  ->  zpart (zgemm w, S4r)
//  region B [2,097,152 .. 3,145,728): part1 (S1w, S2r)  ->  T in first 524,288
//  WfT   [3,145,728 .. 3,211,264)   (S2w, zgemm r)
//  bf    [3,211,264 .. 3,211,296)   (S1w, S4r)
//  bpart [3,211,296 .. 3,227,680)   (S2w, table r)   [8][2048]
//  part2 [3,311,648 .. 3,835,936)   (S2w, table r)   [8][32][2048]
#define WS_UPWT   0
#define WS_ZPART  0
#define WS_PART1  2097152
#define WS_T      2097152
#define WS_WFT    3145728
#define WS_BF     3211264
#define WS_BPART  3211296
#define WS_PART2  3311648

// ---------------------------------------------------------------------------
// S1: blocks [0,2048) transpose up_w -> up_wT
//     blocks [2048,2176) WfT partials: part1[kc][c][2048] over h-chunks of 64
//     block  2176        bf[c] = pin_b[c] + pin_w @ down_b
__global__ __launch_bounds__(256) void k_stage1(
    const float* __restrict__ up_w, const float* __restrict__ pin_w,
    const float* __restrict__ pin_b, const float* __restrict__ down_w,
    const float* __restrict__ down_b, float* __restrict__ ws) {
    int bid = blockIdx.x, tid = threadIdx.x;
    if (bid < 2048) {
        __shared__ float tile[32][33];
        float* up_wT = ws + WS_UPWT;
        int h0 = (bid & 31) * 32;            // over HID
        int o0 = (bid >> 5) * 32;            // over OUTF
        int tx = tid & 31, ty = tid >> 5;    // 32x8
        #pragma unroll
        for (int j = 0; j < 32; j += 8)
            tile[ty + j][tx] = up_w[(o0 + ty + j) * HID + h0 + tx];
        __syncthreads();
        #pragma unroll
        for (int j = 0; j < 32; j += 8)
            up_wT[(h0 + ty + j) * OUTF + o0 + tx] = tile[tx][ty + j];
    } else if (bid < 2176) {
        float* part1 = ws + WS_PART1;
        int b  = bid - 2048;
        int i  = (b & 7) * 256 + tid;
        int k0 = (b >> 3) * 64;
        float acc[32];
        #pragma unroll
        for (int c = 0; c < 32; c++) acc[c] = 0.f;
        #pragma unroll 4
        for (int j = 0; j < 64; j++) {
            float xv = down_w[(k0 + j) * 2048 + i];
            #pragma unroll
            for (int c = 0; c < 32; c++)
                acc[c] = fmaf(pin_w[c * HID + k0 + j], xv, acc[c]);
        }
        #pragma unroll
        for (int c = 0; c < 32; c++)
            part1[((b >> 3) * 32 + c) * 2048 + i] = acc[c];
    } else {
        __shared__ float red[256];
        float* bf = ws + WS_BF;
        int c = tid >> 3, seg = tid & 7;
        float s = 0.f;
        #pragma unroll 8
        for (int k = seg * 128; k < seg * 128 + 128; k++)
            s = fmaf(pin_w[c * HID + k], down_b[k], s);
        red[tid] = s;
        __syncthreads();
        if (tid < 32) {
            float t = pin_b[tid];
            #pragma unroll
            for (int q = 0; q < 8; q++) t += red[tid * 8 + q];
            bf[tid] = t;
        }
    }
}

// ---------------------------------------------------------------------------
// S2: blocks [0,256)   WfT[i*32+c] = sum of 16 part1 partials
//     blocks [256,320) U2c partials part2[hc][c][2048] over h-chunks of 128,
//                      with bpart[hc][o] (bias2 partial) fused on the same xv
__global__ __launch_bounds__(256) void k_stage2(
    const float* __restrict__ pout_w, const float* __restrict__ pout_b,
    const float* __restrict__ up_b, float* __restrict__ ws) {
    int bid = blockIdx.x, tid = threadIdx.x;
    if (bid < 256) {
        const float* part1 = ws + WS_PART1;
        float* WfT = ws + WS_WFT;
        int f = bid * 256 + tid;             // 0..65535
        int i = f & 2047, c = f >> 11;
        float s = 0.f;
        #pragma unroll
        for (int b = 0; b < 16; b++) s += part1[b * 65536 + c * 2048 + i];
        WfT[i * 32 + c] = s;
    } else {
        const float* up_wT = ws + WS_UPWT;
        float* part2 = ws + WS_PART2;
        float* bpart = ws + WS_BPART;
        int b  = bid - 256;
        int i  = (b & 7) * 256 + tid;        // o
        int hc = b >> 3;                     // 0..7
        int k0 = hc * 128;
        float acc[32];
        #pragma unroll
        for (int c = 0; c < 32; c++) acc[c] = 0.f;
        float accb = 0.f;
        #pragma unroll 4
        for (int j = 0; j < 128; j++) {
            float xv = up_wT[(k0 + j) * 2048 + i];
            accb = fmaf(pout_b[k0 + j], xv, accb);   // bias2 fused: reuses xv
            #pragma unroll
            for (int c = 0; c < 32; c++)
                acc[c] = fmaf(pout_w[(k0 + j) * 32 + c], xv, acc[c]);
        }
        #pragma unroll
        for (int c = 0; c < 32; c++)
            part2[(hc * 32 + c) * 2048 + i] = acc[c];
        bpart[hc * 2048 + i] = accb + (hc == 0 ? up_b[i] : 0.f);
    }
}

// ---------------------------------------------------------------------------
// Table (64 blocks): T[n][o] = sum_hc bpart + sum_c cb[n][c]*U2c[c][o]
//     (U2c reduced from part2 in-register; no U2c buffer)
__global__ __launch_bounds__(256) void k_table(
    const float* __restrict__ cb, float* __restrict__ ws) {
    const float* part2 = ws + WS_PART2;
    const float* bpart = ws + WS_BPART;
    float* T = ws + WS_T;
    int bid = blockIdx.x, tid = threadIdx.x;
    int o  = (bid & 7) * 256 + tid;
    int n0 = (bid >> 3) * 32;
    float u[32];
    #pragma unroll
    for (int c = 0; c < 32; c++) {
        float s = 0.f;
        #pragma unroll
        for (int kc = 0; kc < 8; kc++)
            s += part2[(kc * 32 + c) * 2048 + o];
        u[c] = s;
    }
    float bsum = 0.f;
    #pragma unroll
    for (int hc = 0; hc < 8; hc++) bsum += bpart[hc * 2048 + o];
    for (int n = n0; n < n0 + 32; n++) {
        float s = bsum;
        #pragma unroll
        for (int c = 0; c < 32; c++)
            s = fmaf(cb[n * 32 + c], u[c], s);       // cb wave-uniform -> s_load
        T[n * 2048 + o] = s;
    }
}

// ---------------------------------------------------------------------------
// z partial GEMM, register-double-buffered. grid (256, KB), 4 blocks/CU.
// Wave w owns k-quarter [w*32, w*32+32) of each 128-k chunk, all 32 c-cols.
// launch_bounds(256,4): VGPR cap 128 — enough for acc[32]+r[8xfloat4]+addrs,
// so the 8 staging loads of chunk sc+1 stay in flight under chunk sc's FMAs.
// FMA/accumulation order bit-identical to the proven round-1 path.
__global__ __launch_bounds__(256, 4) void k_zgemm(
    const float* __restrict__ x, const float* __restrict__ WfT,
    float* __restrict__ zpart) {
    __shared__ float4 xs[64 * 33 + 1];       // 33808 B -> 4 blocks/CU
    int tid  = threadIdx.x;
    int lane = tid & 63;
    int w    = __builtin_amdgcn_readfirstlane(tid >> 6);  // k-quarter 0..3
    int m0   = blockIdx.x * 64;
    int kb   = blockIdx.y;
    const float* xb = x + (size_t)m0 * 2048 + kb * 512;

    float acc[32];
    #pragma unroll
    for (int c = 0; c < 32; c++) acc[c] = 0.f;

    // prologue: load chunk 0 into registers
    float4 r[8];
    #pragma unroll
    for (int j = 0; j < 8; j++) {
        int f = j * 256 + tid;
        int t = f >> 5, q = f & 31;
        r[j] = *(const float4*)(xb + (size_t)t * 2048 + q * 4);
    }

    for (int sc = 0; sc < 4; sc++) {
        __syncthreads();                     // xs free (prev compute done)
        #pragma unroll
        for (int j = 0; j < 8; j++) {
            int f = j * 256 + tid;
            int t = f >> 5, q = f & 31;
            xs[t * 33 + q] = r[j];
        }
        __syncthreads();                     // xs ready
        if (sc < 3) {                        // issue next chunk: hides HBM lat
            int k0n = (sc + 1) * 128;
            #pragma unroll
            for (int j = 0; j < 8; j++) {
                int f = j * 256 + tid;
                int t = f >> 5, q = f & 31;
                r[j] = *(const float4*)(xb + (size_t)t * 2048 + k0n + q * 4);
            }
        }
        const float* wr = WfT + (size_t)(kb * 512 + sc * 128 + w * 32) * 32;
        #pragma unroll 2
        for (int j = 0; j < 8; j++) {
            float4 xv = xs[lane * 33 + w * 8 + j];
            #pragma unroll
            for (int c = 0; c < 32; c++) {
                acc[c] = fmaf(wr[(j * 4 + 0) * 32 + c], xv.x, acc[c]);
                acc[c] = fmaf(wr[(j * 4 + 1) * 32 + c], xv.y, acc[c]);
                acc[c] = fmaf(wr[(j * 4 + 2) * 32 + c], xv.z, acc[c]);
                acc[c] = fmaf(wr[(j * 4 + 3) * 32 + c], xv.w, acc[c]);
            }
        }
    }

    // deterministic cross-wave reduce: rp[w][t][c], stride 33 (same as before)
    __syncthreads();
    float* rp = (float*)xs;
    #pragma unroll
    for (int c = 0; c < 32; c++)
        rp[(w * 64 + lane) * 33 + c] = acc[c];
    __syncthreads();
    int t  = tid >> 2;
    int cq = (tid & 3) * 8;
    float s[8];
    #pragma unroll
    for (int j = 0; j < 8; j++) {
        float v = rp[(0 * 64 + t) * 33 + cq + j];
        #pragma unroll
        for (int ww = 1; ww < 4; ww++) v += rp[(ww * 64 + t) * 33 + cq + j];
        s[j] = v;
    }
    float* zp = zpart + ((size_t)kb * TOK + m0 + t) * 32 + cq;
    *(float4*)zp       = make_float4(s[0], s[1], s[2], s[3]);
    *(float4*)(zp + 4) = make_float4(s[4], s[5], s[6], s[7]);
}

// ---------------------------------------------------------------------------
// S4: reduce zpart + bias, argmin over 256 codes, fused gather-write of out
// rows from T (clipped). 64 tokens/block, grid=256.
__global__ __launch_bounds__(256) void k_stage4(
    const float* __restrict__ zpart, const float* __restrict__ bf,
    const float* __restrict__ T, const float* __restrict__ cb,
    float* __restrict__ out, float* __restrict__ idx_f, float* __restrict__ loss) {
    __shared__ float z_s[64 * 36];
    __shared__ float cbs[256 * 36];
    __shared__ float cbn[256];
    __shared__ float red_d[256];
    __shared__ int   red_i[256];
    __shared__ int   idx_s[64];

    int tid  = threadIdx.x;
    int lane = tid & 63;
    int w    = __builtin_amdgcn_readfirstlane(tid >> 6);
    int m0   = blockIdx.x * 64;

    // reduce KB partials + bias -> z_s  (coalesced reads)
    #pragma unroll
    for (int i = 0; i < 8; i++) {
        int f = i * 256 + tid;                // 0..2047
        int t = f >> 5, c = f & 31;
        float s = bf[c];
        #pragma unroll
        for (int kb = 0; kb < KB; kb++)
            s += zpart[((size_t)kb * TOK + m0 + t) * 32 + c];
        z_s[t * 36 + c] = s;
    }
    // stage codebook, rows of 36 (16B aligned)
    #pragma unroll
    for (int j = 0; j < 8; j++) {
        int f = j * 256 + tid;                // float4 id, 2048 total
        int n = f >> 3, q = f & 7;
        float4 v = *(const float4*)(cb + n * 32 + q * 4);
        cbs[n * 36 + q * 4 + 0] = v.x;
        cbs[n * 36 + q * 4 + 1] = v.y;
        cbs[n * 36 + q * 4 + 2] = v.z;
        cbs[n * 36 + q * 4 + 3] = v.w;
    }
    __syncthreads();
    {   // cbn[n] = |cb_n|^2
        float s = 0.f;
        #pragma unroll
        for (int q = 0; q < 8; q++) {
            float4 v = *(const float4*)(&cbs[tid * 36 + q * 4]);
            s += v.x * v.x + v.y * v.y + v.z * v.z + v.w * v.w;
        }
        cbn[tid] = s;
    }
    __syncthreads();

    // token = lane, wave w scans codes [64w, 64w+64)
    float z[32];
    #pragma unroll
    for (int q = 0; q < 8; q++) {
        float4 v = *(const float4*)(&z_s[lane * 36 + q * 4]);
        z[q * 4 + 0] = v.x; z[q * 4 + 1] = v.y; z[q * 4 + 2] = v.z; z[q * 4 + 3] = v.w;
    }
    float bd = 3.4e38f; int bi = 0;
    for (int t = 0; t < 64; t++) {
        int n = w * 64 + t;                   // wave-uniform -> LDS broadcast
        float s = 0.f;
        #pragma unroll
        for (int q = 0; q < 8; q++) {
            float4 v = *(const float4*)(&cbs[n * 36 + q * 4]);
            s = fmaf(v.x, z[q * 4 + 0], s);
            s = fmaf(v.y, z[q * 4 + 1], s);
            s = fmaf(v.z, z[q * 4 + 2], s);
            s = fmaf(v.w, z[q * 4 + 3], s);
        }
        float d = fmaf(-2.f, s, cbn[n]);
        if (d < bd) { bd = d; bi = n; }       // strict < : first min wins
    }
    red_d[w * 64 + lane] = bd;
    red_i[w * 64 + lane] = bi;
    __syncthreads();
    if (tid < 64) {
        float d0 = red_d[tid]; int i0 = red_i[tid];
        #pragma unroll
        for (int ww = 1; ww < 4; ww++) {      // ascending wave = ascending code range
            float d1 = red_d[ww * 64 + tid];
            int   i1 = red_i[ww * 64 + tid];
            if (d1 < d0) { d0 = d1; i0 = i1; }
        }
        idx_s[tid] = i0;
        idx_f[m0 + tid] = (float)i0;
    }
    __syncthreads();

    // fused gather: write 64 rows of T (clipped); T is L2-resident (2 MB)
    const float4* T4 = (const float4*)T;
    float4* O4 = (float4*)(out + (size_t)m0 * 2048);
    #pragma unroll 2
    for (int rr = 0; rr < 64; rr++) {
        int n = idx_s[rr];
        const float4* Tr = T4 + (size_t)n * 512;
        float4 v0 = Tr[tid];
        float4 v1 = Tr[256 + tid];
        v0.x = fminf(fmaxf(v0.x, -1.f), 1.f);
        v0.y = fminf(fmaxf(v0.y, -1.f), 1.f);
        v0.z = fminf(fmaxf(v0.z, -1.f), 1.f);
        v0.w = fminf(fmaxf(v0.w, -1.f), 1.f);
        v1.x = fminf(fmaxf(v1.x, -1.f), 1.f);
        v1.y = fminf(fmaxf(v1.y, -1.f), 1.f);
        v1.z = fminf(fmaxf(v1.z, -1.f), 1.f);
        v1.w = fminf(fmaxf(v1.w, -1.f), 1.f);
        O4[(size_t)rr * 512 + tid]       = v0;
        O4[(size_t)rr * 512 + 256 + tid] = v1;
    }
    if (blockIdx.x == 0 && tid == 0) *loss = 0.f;
}

// ---------------------------------------------------------------------------
extern "C" void kernel_launch(void* const* d_in, const int* in_sizes, int n_in,
                              void* d_out, int out_size, void* d_ws, size_t ws_size,
                              hipStream_t stream) {
    const float* x      = (const float*)d_in[0];
    const float* down_w = (const float*)d_in[1];
    const float* down_b = (const float*)d_in[2];
    const float* pin_w  = (const float*)d_in[3];
    const float* pin_b  = (const float*)d_in[4];
    const float* cb     = (const float*)d_in[5];
    const float* pout_w = (const float*)d_in[6];
    const float* pout_b = (const float*)d_in[7];
    const float* up_w   = (const float*)d_in[8];
    const float* up_b   = (const float*)d_in[9];

    float* ws = (float*)d_ws;
    float* zpart = ws + WS_ZPART;
    float* WfT   = ws + WS_WFT;
    float* bf    = ws + WS_BF;
    float* T     = ws + WS_T;

    float* out_f  = (float*)d_out;                   // [16384][2048]
    float* idx_f  = out_f + (size_t)TOK * OUTF;      // [16384]
    float* loss_f = idx_f + TOK;                     // [1]

    k_stage1<<<2177, 256, 0, stream>>>(up_w, pin_w, pin_b, down_w, down_b, ws);
    k_stage2<<<320,  256, 0, stream>>>(pout_w, pout_b, up_b, ws);
    k_table<<<64,    256, 0, stream>>>(cb, ws);
    k_zgemm<<<dim3(256, KB), 256, 0, stream>>>(x, WfT, zpart);
    k_stage4<<<256,  256, 0, stream>>>(zpart, bf, T, cb, out_f, idx_f, loss_f);
}

// Round 4
// 387.935 us; speedup vs baseline: 1.4020x; 1.1631x over previous
//
#include <hip/hip_runtime.h>

// Problem dims
#define TOK   16384   // B*S
#define INFT  2048
#define HID   1024
#define CBD   32
#define NC    256
#define OUTF  2048
#define KB    4       // k-split chunks for z GEMM (512 k each)

// ---------------------------------------------------------------------------
// ws layout (float offsets) — lifetime-sequenced aliasing
//  region A [0 .. 2,097,152):         up_wT (S1w, S2r)  ->  zpart (zmain w, S4r)
//  region B [2,097,152 .. 3,145,728): part1 (S1w, S2r)  ->  T in first 524,288
//  WfT   [3,145,728 .. 3,211,264)   (S2w, zmain r)
//  bf    [3,211,264 .. 3,211,296)   (S1w, S4r)
//  bpart [3,211,296 .. 3,227,680)   (S2w, zmain-table r)   [8][2048]
//  part2 [3,311,648 .. 3,835,936)   (S2w, zmain-table r)   [8][32][2048]
#define WS_UPWT   0
#define WS_ZPART  0
#define WS_PART1  2097152
#define WS_T      2097152
#define WS_WFT    3145728
#define WS_BF     3211264
#define WS_BPART  3211296
#define WS_PART2  3311648

// ---------------------------------------------------------------------------
// S1: blocks [0,2048) transpose up_w -> up_wT
//     blocks [2048,2176) WfT partials: part1[kc][c][2048] over h-chunks of 64
//     block  2176        bf[c] = pin_b[c] + pin_w @ down_b
__global__ __launch_bounds__(256) void k_stage1(
    const float* __restrict__ up_w, const float* __restrict__ pin_w,
    const float* __restrict__ pin_b, const float* __restrict__ down_w,
    const float* __restrict__ down_b, float* __restrict__ ws) {
    int bid = blockIdx.x, tid = threadIdx.x;
    if (bid < 2048) {
        __shared__ float tile[32][33];
        float* up_wT = ws + WS_UPWT;
        int h0 = (bid & 31) * 32;            // over HID
        int o0 = (bid >> 5) * 32;            // over OUTF
        int tx = tid & 31, ty = tid >> 5;    // 32x8
        #pragma unroll
        for (int j = 0; j < 32; j += 8)
            tile[ty + j][tx] = up_w[(o0 + ty + j) * HID + h0 + tx];
        __syncthreads();
        #pragma unroll
        for (int j = 0; j < 32; j += 8)
            up_wT[(h0 + ty + j) * OUTF + o0 + tx] = tile[tx][ty + j];
    } else if (bid < 2176) {
        float* part1 = ws + WS_PART1;
        int b  = bid - 2048;
        int i  = (b & 7) * 256 + tid;
        int k0 = (b >> 3) * 64;
        float acc[32];
        #pragma unroll
        for (int c = 0; c < 32; c++) acc[c] = 0.f;
        #pragma unroll 4
        for (int j = 0; j < 64; j++) {
            float xv = down_w[(k0 + j) * 2048 + i];
            #pragma unroll
            for (int c = 0; c < 32; c++)
                acc[c] = fmaf(pin_w[c * HID + k0 + j], xv, acc[c]);
        }
        #pragma unroll
        for (int c = 0; c < 32; c++)
            part1[((b >> 3) * 32 + c) * 2048 + i] = acc[c];
    } else {
        __shared__ float red[256];
        float* bf = ws + WS_BF;
        int c = tid >> 3, seg = tid & 7;
        float s = 0.f;
        #pragma unroll 8
        for (int k = seg * 128; k < seg * 128 + 128; k++)
            s = fmaf(pin_w[c * HID + k], down_b[k], s);
        red[tid] = s;
        __syncthreads();
        if (tid < 32) {
            float t = pin_b[tid];
            #pragma unroll
            for (int q = 0; q < 8; q++) t += red[tid * 8 + q];
            bf[tid] = t;
        }
    }
}

// ---------------------------------------------------------------------------
// S2: blocks [0,256)   WfT[i*32+c] = sum of 16 part1 partials
//     blocks [256,320) U2c partials part2[hc][c][2048] over h-chunks of 128,
//                      with bpart[hc][o] (bias2 partial) fused on the same xv
__global__ __launch_bounds__(256) void k_stage2(
    const float* __restrict__ pout_w, const float* __restrict__ pout_b,
    const float* __restrict__ up_b, float* __restrict__ ws) {
    int bid = blockIdx.x, tid = threadIdx.x;
    if (bid < 256) {
        const float* part1 = ws + WS_PART1;
        float* WfT = ws + WS_WFT;
        int f = bid * 256 + tid;             // 0..65535
        int i = f & 2047, c = f >> 11;
        float s = 0.f;
        #pragma unroll
        for (int b = 0; b < 16; b++) s += part1[b * 65536 + c * 2048 + i];
        WfT[i * 32 + c] = s;
    } else {
        const float* up_wT = ws + WS_UPWT;
        float* part2 = ws + WS_PART2;
        float* bpart = ws + WS_BPART;
        int b  = bid - 256;
        int i  = (b & 7) * 256 + tid;        // o
        int hc = b >> 3;                     // 0..7
        int k0 = hc * 128;
        float acc[32];
        #pragma unroll
        for (int c = 0; c < 32; c++) acc[c] = 0.f;
        float accb = 0.f;
        #pragma unroll 4
        for (int j = 0; j < 128; j++) {
            float xv = up_wT[(k0 + j) * 2048 + i];
            accb = fmaf(pout_b[k0 + j], xv, accb);   // bias2 fused: reuses xv
            #pragma unroll
            for (int c = 0; c < 32; c++)
                acc[c] = fmaf(pout_w[(k0 + j) * 32 + c], xv, acc[c]);
        }
        #pragma unroll
        for (int c = 0; c < 32; c++)
            part2[(hc * 32 + c) * 2048 + i] = acc[c];
        bpart[hc * 2048 + i] = accb + (hc == 0 ? up_b[i] : 0.f);
    }
}

// ---------------------------------------------------------------------------
// Stage chunk ch_ (128 k) of this block's x panel into LDS buffer dstbuf via
// async global_load_lds (zero staging VGPRs). LDS dest is wave-linear:
// granule (w*8+j)*64+lane = (row, colp=lane&31). Source pre-swizzled so that
// (row, colp) holds logical col (colp ^ (row&31)) — both-sides involution;
// each instruction still reads two contiguous 512B spans (coalesced).
#define STAGE_CHUNK(dstbuf, ch_)                                              \
    {                                                                         \
        const float* sb_ = xb + (ch_) * 128;                                  \
        _Pragma("unroll")                                                     \
        for (int j = 0; j < 8; j++) {                                         \
            int row_  = (w * 8 + j) * 2 + (lane >> 5);                        \
            int clog_ = (lane & 31) ^ (row_ & 31);                            \
            const float* srcp_ = sb_ + (size_t)row_ * 2048 + clog_ * 4;       \
            __builtin_amdgcn_global_load_lds(                                 \
                (const __attribute__((address_space(1))) void*)srcp_,         \
                (__attribute__((address_space(3))) void*)((dstbuf) + (w * 8 + j) * 64), \
                16, 0, 0);                                                    \
        }                                                                     \
    }

// ---------------------------------------------------------------------------
// zmain: blocks [0,64)    table: T[n][o] = sum_hc bpart + sum_c cb[n][c]*U2c
//        blocks [64,1088) z partial GEMM, double-buffered LDS + async
//                         global_load_lds, depth-1 prefetch. FMA order,
//                         cross-wave reduce order, zpart layout bit-identical
//                         to the proven round-1 path.
__global__ __launch_bounds__(256, 4) void k_zmain(
    const float* __restrict__ x, const float* __restrict__ cb,
    const float* __restrict__ WfT, float* __restrict__ ws) {
    __shared__ float4 buf2[2][64 * 32];      // 2 x 32 KiB = 64 KiB exactly
    int bid = blockIdx.x, tid = threadIdx.x;
    if (bid < 64) {
        const float* part2 = ws + WS_PART2;
        const float* bpart = ws + WS_BPART;
        float* T = ws + WS_T;
        int o  = (bid & 7) * 256 + tid;
        int n0 = (bid >> 3) * 32;
        float u[32];
        #pragma unroll
        for (int c = 0; c < 32; c++) {
            float s = 0.f;
            #pragma unroll
            for (int kc = 0; kc < 8; kc++)
                s += part2[(kc * 32 + c) * 2048 + o];
            u[c] = s;
        }
        float bsum = 0.f;
        #pragma unroll
        for (int hc = 0; hc < 8; hc++) bsum += bpart[hc * 2048 + o];
        for (int n = n0; n < n0 + 32; n++) {
            float s = bsum;
            #pragma unroll
            for (int c = 0; c < 32; c++)
                s = fmaf(cb[n * 32 + c], u[c], s);   // cb wave-uniform -> s_load
            T[n * 2048 + o] = s;
        }
        return;
    }

    float* zpart = ws + WS_ZPART;
    int b    = bid - 64;
    int lane = tid & 63;
    int w    = __builtin_amdgcn_readfirstlane(tid >> 6);  // k-quarter 0..3
    int m0   = (b & 255) * 64;
    int kb   = b >> 8;
    const float* xb = x + (size_t)m0 * 2048 + kb * 512;
    int l5 = lane & 31;

    float acc[32];
    #pragma unroll
    for (int c = 0; c < 32; c++) acc[c] = 0.f;

    // prologue: stage chunk 0; __syncthreads drains vmcnt(0) -> data visible
    STAGE_CHUNK(buf2[0], 0);
    __syncthreads();

    for (int ch = 0; ch < 4; ch++) {
        // issue next chunk's async loads first — they complete under compute
        if (ch < 3) STAGE_CHUNK(buf2[(ch + 1) & 1], ch + 1);
        const float4* bcur = buf2[ch & 1];
        const float* wr = WfT + (size_t)(kb * 512 + ch * 128 + w * 32) * 32;
        #pragma unroll 2
        for (int j = 0; j < 8; j++) {
            // read with the same involution: colp = (w*8+j) ^ (lane&31)
            float4 xv = bcur[lane * 32 + ((w * 8 + j) ^ l5)];
            #pragma unroll
            for (int c = 0; c < 32; c++) {
                acc[c] = fmaf(wr[(j * 4 + 0) * 32 + c], xv.x, acc[c]);
                acc[c] = fmaf(wr[(j * 4 + 1) * 32 + c], xv.y, acc[c]);
                acc[c] = fmaf(wr[(j * 4 + 2) * 32 + c], xv.z, acc[c]);
                acc[c] = fmaf(wr[(j * 4 + 3) * 32 + c], xv.w, acc[c]);
            }
        }
        __syncthreads();   // drains prefetch vmcnt + all waves done reading bcur
    }

    // deterministic cross-wave reduce: rp[w][t][c], stride 33 — identical to
    // round-1 order. rp (33.8 KB) aliases the dead LDS buffers (64 KB).
    float* rp = (float*)buf2;
    #pragma unroll
    for (int c = 0; c < 32; c++)
        rp[(w * 64 + lane) * 33 + c] = acc[c];
    __syncthreads();
    int t  = tid >> 2;
    int cq = (tid & 3) * 8;
    float s[8];
    #pragma unroll
    for (int j = 0; j < 8; j++) {
        float v = rp[(0 * 64 + t) * 33 + cq + j];
        #pragma unroll
        for (int ww = 1; ww < 4; ww++) v += rp[(ww * 64 + t) * 33 + cq + j];
        s[j] = v;
    }
    float* zp = zpart + ((size_t)kb * TOK + m0 + t) * 32 + cq;
    *(float4*)zp       = make_float4(s[0], s[1], s[2], s[3]);
    *(float4*)(zp + 4) = make_float4(s[4], s[5], s[6], s[7]);
}

// ---------------------------------------------------------------------------
// S4: reduce zpart + bias, argmin over 256 codes, fused gather-write of out
// rows from T (clipped). 64 tokens/block, grid=256.
__global__ __launch_bounds__(256) void k_stage4(
    const float* __restrict__ zpart, const float* __restrict__ bf,
    const float* __restrict__ T, const float* __restrict__ cb,
    float* __restrict__ out, float* __restrict__ idx_f, float* __restrict__ loss) {
    __shared__ float z_s[64 * 36];
    __shared__ float cbs[256 * 36];
    __shared__ float cbn[256];
    __shared__ float red_d[256];
    __shared__ int   red_i[256];
    __shared__ int   idx_s[64];

    int tid  = threadIdx.x;
    int lane = tid & 63;
    int w    = __builtin_amdgcn_readfirstlane(tid >> 6);
    int m0   = blockIdx.x * 64;

    // reduce KB partials + bias -> z_s  (coalesced reads)
    #pragma unroll
    for (int i = 0; i < 8; i++) {
        int f = i * 256 + tid;                // 0..2047
        int t = f >> 5, c = f & 31;
        float s = bf[c];
        #pragma unroll
        for (int kb = 0; kb < KB; kb++)
            s += zpart[((size_t)kb * TOK + m0 + t) * 32 + c];
        z_s[t * 36 + c] = s;
    }
    // stage codebook, rows of 36 (16B aligned)
    #pragma unroll
    for (int j = 0; j < 8; j++) {
        int f = j * 256 + tid;                // float4 id, 2048 total
        int n = f >> 3, q = f & 7;
        float4 v = *(const float4*)(cb + n * 32 + q * 4);
        cbs[n * 36 + q * 4 + 0] = v.x;
        cbs[n * 36 + q * 4 + 1] = v.y;
        cbs[n * 36 + q * 4 + 2] = v.z;
        cbs[n * 36 + q * 4 + 3] = v.w;
    }
    __syncthreads();
    {   // cbn[n] = |cb_n|^2
        float s = 0.f;
        #pragma unroll
        for (int q = 0; q < 8; q++) {
            float4 v = *(const float4*)(&cbs[tid * 36 + q * 4]);
            s += v.x * v.x + v.y * v.y + v.z * v.z + v.w * v.w;
        }
        cbn[tid] = s;
    }
    __syncthreads();

    // token = lane, wave w scans codes [64w, 64w+64)
    float z[32];
    #pragma unroll
    for (int q = 0; q < 8; q++) {
        float4 v = *(const float4*)(&z_s[lane * 36 + q * 4]);
        z[q * 4 + 0] = v.x; z[q * 4 + 1] = v.y; z[q * 4 + 2] = v.z; z[q * 4 + 3] = v.w;
    }
    float bd = 3.4e38f; int bi = 0;
    for (int t = 0; t < 64; t++) {
        int n = w * 64 + t;                   // wave-uniform -> LDS broadcast
        float s = 0.f;
        #pragma unroll
        for (int q = 0; q < 8; q++) {
            float4 v = *(const float4*)(&cbs[n * 36 + q * 4]);
            s = fmaf(v.x, z[q * 4 + 0], s);
            s = fmaf(v.y, z[q * 4 + 1], s);
            s = fmaf(v.z, z[q * 4 + 2], s);
            s = fmaf(v.w, z[q * 4 + 3], s);
        }
        float d = fmaf(-2.f, s, cbn[n]);
        if (d < bd) { bd = d; bi = n; }       // strict < : first min wins
    }
    red_d[w * 64 + lane] = bd;
    red_i[w * 64 + lane] = bi;
    __syncthreads();
    if (tid < 64) {
        float d0 = red_d[tid]; int i0 = red_i[tid];
        #pragma unroll
        for (int ww = 1; ww < 4; ww++) {      // ascending wave = ascending code range
            float d1 = red_d[ww * 64 + tid];
            int   i1 = red_i[ww * 64 + tid];
            if (d1 < d0) { d0 = d1; i0 = i1; }
        }
        idx_s[tid] = i0;
        idx_f[m0 + tid] = (float)i0;
    }
    __syncthreads();

    // fused gather: write 64 rows of T (clipped); T is L2-resident (2 MB)
    const float4* T4 = (const float4*)T;
    float4* O4 = (float4*)(out + (size_t)m0 * 2048);
    #pragma unroll 2
    for (int rr = 0; rr < 64; rr++) {
        int n = idx_s[rr];
        const float4* Tr = T4 + (size_t)n * 512;
        float4 v0 = Tr[tid];
        float4 v1 = Tr[256 + tid];
        v0.x = fminf(fmaxf(v0.x, -1.f), 1.f);
        v0.y = fminf(fmaxf(v0.y, -1.f), 1.f);
        v0.z = fminf(fmaxf(v0.z, -1.f), 1.f);
        v0.w = fminf(fmaxf(v0.w, -1.f), 1.f);
        v1.x = fminf(fmaxf(v1.x, -1.f), 1.f);
        v1.y = fminf(fmaxf(v1.y, -1.f), 1.f);
        v1.z = fminf(fmaxf(v1.z, -1.f), 1.f);
        v1.w = fminf(fmaxf(v1.w, -1.f), 1.f);
        O4[(size_t)rr * 512 + tid]       = v0;
        O4[(size_t)rr * 512 + 256 + tid] = v1;
    }
    if (blockIdx.x == 0 && tid == 0) *loss = 0.f;
}

// ---------------------------------------------------------------------------
extern "C" void kernel_launch(void* const* d_in, const int* in_sizes, int n_in,
                              void* d_out, int out_size, void* d_ws, size_t ws_size,
                              hipStream_t stream) {
    const float* x      = (const float*)d_in[0];
    const float* down_w = (const float*)d_in[1];
    const float* down_b = (const float*)d_in[2];
    const float* pin_w  = (const float*)d_in[3];
    const float* pin_b  = (const float*)d_in[4];
    const float* cb     = (const float*)d_in[5];
    const float* pout_w = (const float*)d_in[6];
    const float* pout_b = (const float*)d_in[7];
    const float* up_w   = (const float*)d_in[8];
    const float* up_b   = (const float*)d_in[9];

    float* ws = (float*)d_ws;
    float* zpart = ws + WS_ZPART;
    float* WfT   = ws + WS_WFT;
    float* bf    = ws + WS_BF;
    float* T     = ws + WS_T;

    float* out_f  = (float*)d_out;                   // [16384][2048]
    float* idx_f  = out_f + (size_t)TOK * OUTF;      // [16384]
    float* loss_f = idx_f + TOK;                     // [1]

    k_stage1<<<2177, 256, 0, stream>>>(up_w, pin_w, pin_b, down_w, down_b, ws);
    k_stage2<<<320,  256, 0, stream>>>(pout_w, pout_b, up_b, ws);
    k_zmain<<<1088,  256, 0, stream>>>(x, cb, WfT, ws);
    k_stage4<<<256,  256, 0, stream>>>(zpart, bf, T, cb, out_f, idx_f, loss_f);
}